// Round 6
// baseline (554.313 us; speedup 1.0000x reference)
//
#include <hip/hip_runtime.h>
#include <hip/hip_bf16.h>
#include <stdint.h>
#include <math.h>

typedef __bf16 bf16;
typedef __attribute__((ext_vector_type(8))) __bf16 bf16x8;
typedef __attribute__((ext_vector_type(4))) float f32x4;

#define MFMA(a, b, c) __builtin_amdgcn_mfma_f32_16x16x32_bf16(a, b, c, 0, 0, 0)

__device__ __forceinline__ bf16x8 cvt8(const float* p) {
  f32x4 a = *(const f32x4*)p;
  f32x4 b = *(const f32x4*)(p + 4);
  bf16x8 o;
  o[0] = (bf16)a[0]; o[1] = (bf16)a[1]; o[2] = (bf16)a[2]; o[3] = (bf16)a[3];
  o[4] = (bf16)b[0]; o[5] = (bf16)b[1]; o[6] = (bf16)b[2]; o[7] = (bf16)b[3];
  return o;
}

// ---------------- mask bit-pack: int32 [B,S,S] -> uint64 words [B*S][S/64] ----
__global__ __launch_bounds__(256) void pack_mask(const int* __restrict__ mask,
                                                 unsigned long long* __restrict__ pm,
                                                 int nwords) {
  const int lane = threadIdx.x & 63;
  const int wave = blockIdx.x * (blockDim.x >> 6) + (threadIdx.x >> 6);
  const int nwaves = gridDim.x * (blockDim.x >> 6);
  for (int w = wave; w < nwords; w += nwaves) {
    int m = mask[(size_t)w * 64 + lane];
    unsigned long long bits = __ballot(m != 0);
    if (lane == 0) pm[w] = bits;
  }
}

// ---------------- GEMM: out = X @ W^T + bias (fp32 in, bf16 MFMA) -------------
// M=4096 N=1024 K=1024. SPLIT=1: bf16 out in [B,H,S,64]; SPLIT=0: fp32 [M,N].
template <int SPLIT>
__global__ __launch_bounds__(256) void gemm_bt(const float* __restrict__ X,
                                               const float* __restrict__ W,
                                               const float* __restrict__ bias,
                                               void* __restrict__ out_) {
  __shared__ __align__(16) bf16 As[128 * 32];
  __shared__ __align__(16) bf16 Bs[128 * 32];
  const int tid = threadIdx.x, lane = tid & 63, w = tid >> 6;
  const int r16 = lane & 15, g4 = lane >> 4;
  const int m0 = blockIdx.x * 128, n0 = blockIdx.y * 128;

  f32x4 acc[4][4] = {};

  // staging map: chunk c in [0,512) covers (row=c>>2, col8=(c&3)*8) of 128x32
  const int ra = tid >> 2;          // rows 0..63 (chunk cc=1 adds 64)
  const int ca = (tid & 3) << 3;    // 0,8,16,24

  for (int k0 = 0; k0 < 1024; k0 += 32) {
    bf16x8 xa0 = cvt8(&X[(size_t)(m0 + ra) * 1024 + k0 + ca]);
    bf16x8 xa1 = cvt8(&X[(size_t)(m0 + 64 + ra) * 1024 + k0 + ca]);
    bf16x8 xb0 = cvt8(&W[(size_t)(n0 + ra) * 1024 + k0 + ca]);
    bf16x8 xb1 = cvt8(&W[(size_t)(n0 + 64 + ra) * 1024 + k0 + ca]);
    __syncthreads();  // previous iteration's LDS reads complete
    *(bf16x8*)&As[ra * 32 + ca] = xa0;
    *(bf16x8*)&As[(ra + 64) * 32 + ca] = xa1;
    *(bf16x8*)&Bs[ra * 32 + ca] = xb0;
    *(bf16x8*)&Bs[(ra + 64) * 32 + ca] = xb1;
    __syncthreads();  // staged

    const int wm = (w >> 1) << 6, wn = (w & 1) << 6;
    bf16x8 af[4], bfr[4];
#pragma unroll
    for (int i = 0; i < 4; i++)
      af[i] = *(const bf16x8*)&As[(wm + i * 16 + r16) * 32 + g4 * 8];
#pragma unroll
    for (int j = 0; j < 4; j++)
      bfr[j] = *(const bf16x8*)&Bs[(wn + j * 16 + r16) * 32 + g4 * 8];
#pragma unroll
    for (int i = 0; i < 4; i++)
#pragma unroll
      for (int j = 0; j < 4; j++)
        acc[i][j] = MFMA(af[i], bfr[j], acc[i][j]);
  }

  const int wm = (w >> 1) << 6, wn = (w & 1) << 6;
#pragma unroll
  for (int j = 0; j < 4; j++) {
    const int col = n0 + wn + j * 16 + r16;
    const float bv = bias[col];
#pragma unroll
    for (int i = 0; i < 4; i++) {
      const int row0 = m0 + wm + i * 16 + g4 * 4;
#pragma unroll
      for (int r = 0; r < 4; r++) {
        float v = acc[i][j][r] + bv;
        const int row = row0 + r;
        if (SPLIT) {
          const int bb = row >> 11, s = row & 2047, h = col >> 6, d = col & 63;
          ((bf16*)out_)[((((size_t)bb * 16 + h) * 2048 + s) << 6) + d] = (bf16)v;
        } else {
          ((float*)out_)[(size_t)row * 1024 + col] = v;
        }
      }
    }
  }
}

// ---------------- flash attention: per (qtile, b*h) block, 4 waves ------------
// Q,K,V in [B*H, S, 64] bf16 (workspace). pm = packed mask. out: [B*S,1024] bf16.
__global__ __launch_bounds__(256) void attn_fwd(const bf16* __restrict__ Q,
                                                const bf16* __restrict__ Kb,
                                                const bf16* __restrict__ Vb,
                                                const unsigned long long* __restrict__ pm,
                                                const float* __restrict__ rel,
                                                bf16* __restrict__ ao) {
  constexpr int PAD = 72;  // 144B rows: 16B-aligned, light bank aliasing
  __shared__ __align__(16) bf16 Ks[64 * PAD];
  __shared__ __align__(16) bf16 Vt[64 * PAD];
  __shared__ __align__(16) bf16 Ps[64 * PAD];
  __shared__ float rb[65];

  const int tid = threadIdx.x, lane = tid & 63, w = tid >> 6;
  const int r16 = lane & 15, g4 = lane >> 4;
  const int qt = blockIdx.x;           // 0..31
  const int bh = blockIdx.y;           // 0..31
  const int b = bh >> 4, h = bh & 15;

  const bf16* Qh = Q + (size_t)bh * 2048 * 64;
  const bf16* Kh = Kb + (size_t)bh * 2048 * 64;
  const bf16* Vh = Vb + (size_t)bh * 2048 * 64;

  // relative-bias row sums (65 entries, fp32 table)
  if (tid < 65) {
    const float* e = rel + tid * 64;
    float s = 0.f;
#pragma unroll
    for (int i = 0; i < 64; i++) s += e[i];
    rb[tid] = s;
  }

  // Q fragments held in registers for the whole block
  bf16x8 aq[2];
  {
    const int qrow = (qt << 6) + (w << 4) + r16;
    aq[0] = *(const bf16x8*)&Qh[(size_t)qrow * 64 + g4 * 8];
    aq[1] = *(const bf16x8*)&Qh[(size_t)qrow * 64 + 32 + g4 * 8];
  }

  f32x4 acc_o[4] = {};
  float mreg[4] = {-1e30f, -1e30f, -1e30f, -1e30f};
  float lreg[4] = {0.f, 0.f, 0.f, 0.f};

  __syncthreads();  // rb visible

  for (int t = 0; t < 32; t++) {
    // ---- stage K tile (row-major) and V tile (plain padded transpose) ----
#pragma unroll
    for (int cc = 0; cc < 2; cc++) {
      const int c = tid + (cc << 8);
      const int key = c >> 3, f8 = (c & 7) << 3;
      bf16x8 kv = *(const bf16x8*)&Kh[(size_t)((t << 6) + key) * 64 + f8];
      *(bf16x8*)&Ks[key * PAD + f8] = kv;
      bf16x8 vv = *(const bf16x8*)&Vh[(size_t)((t << 6) + key) * 64 + f8];
#pragma unroll
      for (int j = 0; j < 8; j++) Vt[(f8 + j) * PAD + key] = vv[j];
    }
    __syncthreads();

    // ---- QK^T: 16x64 scores per wave ----
    f32x4 sc[4];
#pragma unroll
    for (int f = 0; f < 4; f++) {
      f32x4 a = {};
#pragma unroll
      for (int kk = 0; kk < 2; kk++) {
        bf16x8 bk_ = *(const bf16x8*)&Ks[(f * 16 + r16) * PAD + kk * 32 + g4 * 8];
        a = MFMA(aq[kk], bk_, a);
      }
      sc[f] = a;
    }

    // ---- scale + rel-bias + mask (NaN-sanitized diagnostic guard) ----
    unsigned long long mw[4];
    const int qrow0 = (qt << 6) + (w << 4) + (g4 << 2);
#pragma unroll
    for (int r = 0; r < 4; r++)
      mw[r] = pm[(size_t)((b << 11) + qrow0 + r) * 32 + t];

    float s_[4][4];
#pragma unroll
    for (int f = 0; f < 4; f++) {
      const int kcol = (t << 6) + (f << 4) + r16;
#pragma unroll
      for (int r = 0; r < 4; r++) {
        int dd = (qrow0 + r) - kcol;
        dd = dd < -32 ? -32 : (dd > 32 ? 32 : dd);
        const bool on = (mw[r] >> ((f << 4) + r16)) & 1ull;
        float x = on ? sc[f][r] * 0.125f + rb[dd + 32] : -1e9f;
        s_[f][r] = (x == x) ? x : -1e9f;
      }
    }

    // ---- online softmax (row reduce across 16 lanes) ----
    float rs[4];
#pragma unroll
    for (int r = 0; r < 4; r++) {
      float v = fmaxf(fmaxf(s_[0][r], s_[1][r]), fmaxf(s_[2][r], s_[3][r]));
#pragma unroll
      for (int d = 1; d < 16; d <<= 1) v = fmaxf(v, __shfl_xor(v, d, 16));
      const float mn = fmaxf(mreg[r], v);
      rs[r] = __expf(mreg[r] - mn);
      mreg[r] = mn;
    }
    float ps_[4] = {0.f, 0.f, 0.f, 0.f};
#pragma unroll
    for (int f = 0; f < 4; f++)
#pragma unroll
      for (int r = 0; r < 4; r++) {
        const float p = __expf(s_[f][r] - mreg[r]);
        ps_[r] += p;
        Ps[(w * 16 + g4 * 4 + r) * PAD + f * 16 + r16] = (bf16)p;
      }
#pragma unroll
    for (int r = 0; r < 4; r++) {
      float v = ps_[r];
#pragma unroll
      for (int d = 1; d < 16; d <<= 1) v += __shfl_xor(v, d, 16);
      lreg[r] = lreg[r] * rs[r] + v;
    }
#pragma unroll
    for (int f = 0; f < 4; f++)
#pragma unroll
      for (int r = 0; r < 4; r++) acc_o[f][r] *= rs[r];

    // ---- PV: O[16x64] += P[16x64] * V[64x64] ----
#pragma unroll
    for (int kk = 0; kk < 2; kk++) {
      bf16x8 ap = *(const bf16x8*)&Ps[(w * 16 + r16) * PAD + kk * 32 + g4 * 8];
#pragma unroll
      for (int f = 0; f < 4; f++) {
        const int d = f * 16 + r16;
        bf16x8 bv_ = *(const bf16x8*)&Vt[d * PAD + kk * 32 + g4 * 8];
        acc_o[f] = MFMA(ap, bv_, acc_o[f]);
      }
    }
    __syncthreads();  // protect Ks/Vt before next tile's staging
  }

  // ---- epilogue: normalize and write [B*S, H*64] bf16 ----
  const int qrow0 = (qt << 6) + (w << 4) + (g4 << 2);
#pragma unroll
  for (int r = 0; r < 4; r++) {
    const float inv = 1.f / lreg[r];
#pragma unroll
    for (int f = 0; f < 4; f++) {
      float v = acc_o[f][r] * inv;
      ao[(size_t)((b << 11) + qrow0 + r) * 1024 + (h << 6) + f * 16 + r16] = (bf16)v;
    }
  }
}

// ---------------- final GEMM reads bf16 AO + fp32 Wo, writes fp32 -------------
__global__ __launch_bounds__(256) void gemm_out(const bf16* __restrict__ X,
                                                const float* __restrict__ W,
                                                const float* __restrict__ bias,
                                                float* __restrict__ out) {
  __shared__ __align__(16) bf16 As[128 * 32];
  __shared__ __align__(16) bf16 Bs[128 * 32];
  const int tid = threadIdx.x, lane = tid & 63, w = tid >> 6;
  const int r16 = lane & 15, g4 = lane >> 4;
  const int m0 = blockIdx.x * 128, n0 = blockIdx.y * 128;

  f32x4 acc[4][4] = {};
  const int ra = tid >> 2;
  const int ca = (tid & 3) << 3;

  for (int k0 = 0; k0 < 1024; k0 += 32) {
    bf16x8 xa0 = *(const bf16x8*)&X[(size_t)(m0 + ra) * 1024 + k0 + ca];
    bf16x8 xa1 = *(const bf16x8*)&X[(size_t)(m0 + 64 + ra) * 1024 + k0 + ca];
    bf16x8 xb0 = cvt8(&W[(size_t)(n0 + ra) * 1024 + k0 + ca]);
    bf16x8 xb1 = cvt8(&W[(size_t)(n0 + 64 + ra) * 1024 + k0 + ca]);
    __syncthreads();
    *(bf16x8*)&As[ra * 32 + ca] = xa0;
    *(bf16x8*)&As[(ra + 64) * 32 + ca] = xa1;
    *(bf16x8*)&Bs[ra * 32 + ca] = xb0;
    *(bf16x8*)&Bs[(ra + 64) * 32 + ca] = xb1;
    __syncthreads();

    const int wm = (w >> 1) << 6, wn = (w & 1) << 6;
    bf16x8 af[4], bfr[4];
#pragma unroll
    for (int i = 0; i < 4; i++)
      af[i] = *(const bf16x8*)&As[(wm + i * 16 + r16) * 32 + g4 * 8];
#pragma unroll
    for (int j = 0; j < 4; j++)
      bfr[j] = *(const bf16x8*)&Bs[(wn + j * 16 + r16) * 32 + g4 * 8];
#pragma unroll
    for (int i = 0; i < 4; i++)
#pragma unroll
      for (int j = 0; j < 4; j++)
        acc[i][j] = MFMA(af[i], bfr[j], acc[i][j]);
  }

  const int wm = (w >> 1) << 6, wn = (w & 1) << 6;
#pragma unroll
  for (int j = 0; j < 4; j++) {
    const int col = n0 + wn + j * 16 + r16;
    const float bv = bias[col];
#pragma unroll
    for (int i = 0; i < 4; i++) {
      const int row0 = m0 + wm + i * 16 + g4 * 4;
#pragma unroll
      for (int r = 0; r < 4; r++)
        out[(size_t)(row0 + r) * 1024 + col] = acc[i][j][r] + bv;
    }
  }
}

// -----------------------------------------------------------------------------
extern "C" void kernel_launch(void* const* d_in, const int* in_sizes, int n_in,
                              void* d_out, int out_size, void* d_ws, size_t ws_size,
                              hipStream_t stream) {
  const float* query = (const float*)d_in[0];
  const float* key   = (const float*)d_in[1];
  const float* value = (const float*)d_in[2];
  const int*   mask  = (const int*)d_in[3];
  const float* Wq = (const float*)d_in[4];
  const float* bq = (const float*)d_in[5];
  const float* Wk = (const float*)d_in[6];
  const float* bk = (const float*)d_in[7];
  const float* Wv = (const float*)d_in[8];
  const float* bv = (const float*)d_in[9];
  const float* Wo = (const float*)d_in[10];
  const float* bo = (const float*)d_in[11];
  const float* rel = (const float*)d_in[12];

  char* ws = (char*)d_ws;
  bf16* Qb = (bf16*)ws;                       // 8.4 MB  [B*H, S, 64]
  bf16* Kb = (bf16*)(ws + 8388608);           // 8.4 MB
  bf16* Vb = (bf16*)(ws + 16777216);          // 8.4 MB
  bf16* AO = (bf16*)(ws + 25165824);          // 8.4 MB  [B*S, 1024]
  unsigned long long* PM = (unsigned long long*)(ws + 33554432);  // 1 MB

  pack_mask<<<256, 256, 0, stream>>>(mask, PM, 2 * 2048 * 32);

  dim3 g(32, 8);
  gemm_bt<1><<<g, 256, 0, stream>>>(query, Wq, bq, Qb);
  gemm_bt<1><<<g, 256, 0, stream>>>(key,   Wk, bk, Kb);
  gemm_bt<1><<<g, 256, 0, stream>>>(value, Wv, bv, Vb);

  attn_fwd<<<dim3(32, 32), 256, 0, stream>>>(Qb, Kb, Vb, PM, rel, AO);

  gemm_out<<<g, 256, 0, stream>>>(AO, Wo, bo, (float*)d_out);
}

// Round 7
// 458.320 us; speedup vs baseline: 1.2094x; 1.2094x over previous
//
#include <hip/hip_runtime.h>
#include <hip/hip_bf16.h>
#include <stdint.h>
#include <math.h>

typedef __bf16 bf16;
typedef __attribute__((ext_vector_type(8))) __bf16 bf16x8;
typedef __attribute__((ext_vector_type(4))) float f32x4;

#define MFMA(a, b, c) __builtin_amdgcn_mfma_f32_16x16x32_bf16(a, b, c, 0, 0, 0)

__device__ __forceinline__ bf16x8 cvt8(const float* p) {
  f32x4 a = *(const f32x4*)p;
  f32x4 b = *(const f32x4*)(p + 4);
  bf16x8 o;
  o[0] = (bf16)a[0]; o[1] = (bf16)a[1]; o[2] = (bf16)a[2]; o[3] = (bf16)a[3];
  o[4] = (bf16)b[0]; o[5] = (bf16)b[1]; o[6] = (bf16)b[2]; o[7] = (bf16)b[3];
  return o;
}

// ---------------- one-shot fp32 -> bf16 convert of 7 tensors ------------------
__global__ __launch_bounds__(256) void cvt_bf16(
    const float* __restrict__ s0, const float* __restrict__ s1, const float* __restrict__ s2,
    const float* __restrict__ s3, const float* __restrict__ s4, const float* __restrict__ s5,
    const float* __restrict__ s6,
    bf16* __restrict__ d0, bf16* __restrict__ d1, bf16* __restrict__ d2,
    bf16* __restrict__ d3, bf16* __restrict__ d4, bf16* __restrict__ d5,
    bf16* __restrict__ d6) {
  const float* s; bf16* d; int n8;
  switch (blockIdx.y) {
    case 0: s = s0; d = d0; n8 = 524288; break;  // 4096*1024/8
    case 1: s = s1; d = d1; n8 = 524288; break;
    case 2: s = s2; d = d2; n8 = 524288; break;
    case 3: s = s3; d = d3; n8 = 131072; break;  // 1024*1024/8
    case 4: s = s4; d = d4; n8 = 131072; break;
    case 5: s = s5; d = d5; n8 = 131072; break;
    default: s = s6; d = d6; n8 = 131072; break;
  }
  for (int i = blockIdx.x * 256 + threadIdx.x; i < n8; i += gridDim.x * 256)
    *(bf16x8*)&d[(size_t)i * 8] = cvt8(&s[(size_t)i * 8]);
}

// ---------------- mask bit-pack: int32 [B,S,S] -> uint64 words [B*S][S/64] ----
__global__ __launch_bounds__(256) void pack_mask(const int* __restrict__ mask,
                                                 unsigned long long* __restrict__ pm,
                                                 int nwords) {
  const int lane = threadIdx.x & 63;
  const int wave = blockIdx.x * (blockDim.x >> 6) + (threadIdx.x >> 6);
  const int nwaves = gridDim.x * (blockDim.x >> 6);
  for (int w = wave; w < nwords; w += nwaves) {
    int m = mask[(size_t)w * 64 + lane];
    unsigned long long bits = __ballot(m != 0);
    if (lane == 0) pm[w] = bits;
  }
}

// ---------------- GEMM: out = X @ W^T + bias, bf16 in, 128x64 tile ------------
// M=4096 N=1024 K=1024. OUT=1: bf16 out in [B,H,S,64]; OUT=0: fp32 flat [M,N].
// T14 schedule: prologue-stage; loop { load(t+1); MFMA(t); bar; write; bar; }.
template <int OUT>
__global__ __launch_bounds__(256) void gemm_bt(const bf16* __restrict__ X,
                                               const bf16* __restrict__ W,
                                               const float* __restrict__ bias,
                                               void* __restrict__ out_) {
  __shared__ __align__(16) bf16 As[128 * 32];
  __shared__ __align__(16) bf16 Bs[64 * 32];
  const int tid = threadIdx.x, lane = tid & 63, w = tid >> 6;
  const int r16 = lane & 15, g4 = lane >> 4;
  const int m0 = blockIdx.x * 128, n0 = blockIdx.y * 64;

  f32x4 acc[4][2] = {};

  const int ra = tid >> 2;          // 0..63
  const int ca = (tid & 3) << 3;    // 0,8,16,24

  bf16x8 xa0 = *(const bf16x8*)&X[(size_t)(m0 + ra) * 1024 + ca];
  bf16x8 xa1 = *(const bf16x8*)&X[(size_t)(m0 + 64 + ra) * 1024 + ca];
  bf16x8 xb0 = *(const bf16x8*)&W[(size_t)(n0 + ra) * 1024 + ca];
  *(bf16x8*)&As[ra * 32 + ca] = xa0;
  *(bf16x8*)&As[(ra + 64) * 32 + ca] = xa1;
  *(bf16x8*)&Bs[ra * 32 + ca] = xb0;
  __syncthreads();

  const int wm = (w >> 1) << 6, wn = (w & 1) << 5;

  for (int k0 = 0; k0 < 1024; k0 += 32) {
    if (k0 + 32 < 1024) {
      xa0 = *(const bf16x8*)&X[(size_t)(m0 + ra) * 1024 + k0 + 32 + ca];
      xa1 = *(const bf16x8*)&X[(size_t)(m0 + 64 + ra) * 1024 + k0 + 32 + ca];
      xb0 = *(const bf16x8*)&W[(size_t)(n0 + ra) * 1024 + k0 + 32 + ca];
    }
    bf16x8 af[4], bfr[2];
#pragma unroll
    for (int i = 0; i < 4; i++)
      af[i] = *(const bf16x8*)&As[(wm + i * 16 + r16) * 32 + g4 * 8];
#pragma unroll
    for (int j = 0; j < 2; j++)
      bfr[j] = *(const bf16x8*)&Bs[(wn + j * 16 + r16) * 32 + g4 * 8];
#pragma unroll
    for (int i = 0; i < 4; i++)
#pragma unroll
      for (int j = 0; j < 2; j++)
        acc[i][j] = MFMA(af[i], bfr[j], acc[i][j]);
    __syncthreads();
    if (k0 + 32 < 1024) {
      *(bf16x8*)&As[ra * 32 + ca] = xa0;
      *(bf16x8*)&As[(ra + 64) * 32 + ca] = xa1;
      *(bf16x8*)&Bs[ra * 32 + ca] = xb0;
      __syncthreads();
    }
  }

#pragma unroll
  for (int j = 0; j < 2; j++) {
    const int col = n0 + wn + j * 16 + r16;
    const float bv = bias[col];
#pragma unroll
    for (int i = 0; i < 4; i++) {
      const int row0 = m0 + wm + i * 16 + g4 * 4;
#pragma unroll
      for (int r = 0; r < 4; r++) {
        float v = acc[i][j][r] + bv;
        const int row = row0 + r;
        if (OUT) {
          const int bb = row >> 11, s = row & 2047, h = col >> 6, d = col & 63;
          ((bf16*)out_)[((((size_t)bb * 16 + h) * 2048 + s) << 6) + d] = (bf16)v;
        } else {
          ((float*)out_)[(size_t)row * 1024 + col] = v;
        }
      }
    }
  }
}

// ---------------- flash attention: per (qtile, b*h) block, 4 waves ------------
// Q,K,V in [B*H, S, 64] bf16 (workspace). pm = packed mask. out: [B*S,1024] bf16.
// V^T in LDS uses granule-XOR swizzle: elem(d,k) at d*64 + (((k>>3)^(d>>3))<<3) + (k&7).
__global__ __launch_bounds__(256) void attn_fwd(const bf16* __restrict__ Q,
                                                const bf16* __restrict__ Kb,
                                                const bf16* __restrict__ Vb,
                                                const unsigned long long* __restrict__ pm,
                                                const float* __restrict__ rel,
                                                bf16* __restrict__ ao) {
  constexpr int PAD = 72;
  __shared__ __align__(16) bf16 Ks[64 * PAD];
  __shared__ __align__(16) bf16 Vs[64 * 64];   // swizzled V^T
  __shared__ __align__(16) bf16 Ps[64 * PAD];
  __shared__ float rb[65];

  const int tid = threadIdx.x, lane = tid & 63, w = tid >> 6;
  const int r16 = lane & 15, g4 = lane >> 4;
  const int qt = blockIdx.x;           // 0..31
  const int bh = blockIdx.y;           // 0..31
  const int b = bh >> 4, h = bh & 15;

  const bf16* Qh = Q + (size_t)bh * 2048 * 64;
  const bf16* Kh = Kb + (size_t)bh * 2048 * 64;
  const bf16* Vh = Vb + (size_t)bh * 2048 * 64;

  if (tid < 65) {
    const float* e = rel + tid * 64;
    float s = 0.f;
#pragma unroll
    for (int i = 0; i < 64; i++) s += e[i];
    rb[tid] = s;
  }

  bf16x8 aq[2];
  {
    const int qrow = (qt << 6) + (w << 4) + r16;
    aq[0] = *(const bf16x8*)&Qh[(size_t)qrow * 64 + g4 * 8];
    aq[1] = *(const bf16x8*)&Qh[(size_t)qrow * 64 + 32 + g4 * 8];
  }

  f32x4 acc_o[4] = {};
  float mreg[4] = {-1e30f, -1e30f, -1e30f, -1e30f};
  float lreg[4] = {0.f, 0.f, 0.f, 0.f};

  // staging indices: chunk cc covers (key = c>>3, f8 = (c&7)*8)
  int skey[2], sf8[2], svcol[2];
#pragma unroll
  for (int cc = 0; cc < 2; cc++) {
    const int c = tid + (cc << 8);
    skey[cc] = c >> 3;
    sf8[cc] = (c & 7) << 3;
    svcol[cc] = (((skey[cc] >> 3) ^ (c & 7)) << 3) | (skey[cc] & 7);
  }

  bf16x8 kreg[2], vreg[2];
#pragma unroll
  for (int cc = 0; cc < 2; cc++) {
    kreg[cc] = *(const bf16x8*)&Kh[(size_t)skey[cc] * 64 + sf8[cc]];
    vreg[cc] = *(const bf16x8*)&Vh[(size_t)skey[cc] * 64 + sf8[cc]];
  }
#pragma unroll
  for (int cc = 0; cc < 2; cc++) {
    *(bf16x8*)&Ks[skey[cc] * PAD + sf8[cc]] = kreg[cc];
#pragma unroll
    for (int j = 0; j < 8; j++) Vs[((sf8[cc] + j) << 6) | svcol[cc]] = vreg[cc][j];
  }
  __syncthreads();  // staging + rb visible

  for (int t = 0; t < 32; t++) {
    // ---- T14: issue next tile's global loads before compute ----
    if (t < 31) {
#pragma unroll
      for (int cc = 0; cc < 2; cc++) {
        kreg[cc] = *(const bf16x8*)&Kh[(size_t)(((t + 1) << 6) + skey[cc]) * 64 + sf8[cc]];
        vreg[cc] = *(const bf16x8*)&Vh[(size_t)(((t + 1) << 6) + skey[cc]) * 64 + sf8[cc]];
      }
    }
    unsigned long long mw[4];
    const int qrow0 = (qt << 6) + (w << 4) + (g4 << 2);
#pragma unroll
    for (int r = 0; r < 4; r++)
      mw[r] = pm[(size_t)((b << 11) + qrow0 + r) * 32 + t];

    // ---- QK^T: 16x64 scores per wave ----
    f32x4 sc[4];
#pragma unroll
    for (int f = 0; f < 4; f++) {
      f32x4 a = {};
#pragma unroll
      for (int kk = 0; kk < 2; kk++) {
        bf16x8 bk_ = *(const bf16x8*)&Ks[(f * 16 + r16) * PAD + kk * 32 + g4 * 8];
        a = MFMA(aq[kk], bk_, a);
      }
      sc[f] = a;
    }

    // ---- scale + rel-bias + mask ----
    float s_[4][4];
#pragma unroll
    for (int f = 0; f < 4; f++) {
      const int kcol = (t << 6) + (f << 4) + r16;
#pragma unroll
      for (int r = 0; r < 4; r++) {
        int dd = (qrow0 + r) - kcol;
        dd = dd < -32 ? -32 : (dd > 32 ? 32 : dd);
        const bool on = (mw[r] >> ((f << 4) + r16)) & 1ull;
        s_[f][r] = on ? sc[f][r] * 0.125f + rb[dd + 32] : -1e9f;
      }
    }

    // ---- online softmax (row reduce across 16 lanes) ----
    float rs[4];
#pragma unroll
    for (int r = 0; r < 4; r++) {
      float v = fmaxf(fmaxf(s_[0][r], s_[1][r]), fmaxf(s_[2][r], s_[3][r]));
#pragma unroll
      for (int d = 1; d < 16; d <<= 1) v = fmaxf(v, __shfl_xor(v, d, 16));
      const float mn = fmaxf(mreg[r], v);
      rs[r] = __expf(mreg[r] - mn);
      mreg[r] = mn;
    }
    float ps_[4] = {0.f, 0.f, 0.f, 0.f};
#pragma unroll
    for (int f = 0; f < 4; f++)
#pragma unroll
      for (int r = 0; r < 4; r++) {
        const float p = __expf(s_[f][r] - mreg[r]);
        ps_[r] += p;
        Ps[(w * 16 + g4 * 4 + r) * PAD + f * 16 + r16] = (bf16)p;
      }
#pragma unroll
    for (int r = 0; r < 4; r++) {
      float v = ps_[r];
#pragma unroll
      for (int d = 1; d < 16; d <<= 1) v += __shfl_xor(v, d, 16);
      lreg[r] = lreg[r] * rs[r] + v;
    }
#pragma unroll
    for (int f = 0; f < 4; f++)
#pragma unroll
      for (int r = 0; r < 4; r++) acc_o[f][r] *= rs[r];

    // ---- PV: O[16x64] += P[16x64] * V[64x64] (Ps wave-local; Vs swizzled) ----
#pragma unroll
    for (int kk = 0; kk < 2; kk++) {
      bf16x8 ap = *(const bf16x8*)&Ps[(w * 16 + r16) * PAD + kk * 32 + g4 * 8];
#pragma unroll
      for (int f = 0; f < 4; f++) {
        const int d = f * 16 + r16;
        bf16x8 bv_ = *(const bf16x8*)&Vs[(d << 6) | ((((kk << 2) + g4) ^ (d >> 3)) << 3)];
        acc_o[f] = MFMA(ap, bv_, acc_o[f]);
      }
    }
    __syncthreads();  // all waves done reading Ks/Vs
    if (t < 31) {
#pragma unroll
      for (int cc = 0; cc < 2; cc++) {
        *(bf16x8*)&Ks[skey[cc] * PAD + sf8[cc]] = kreg[cc];
#pragma unroll
        for (int j = 0; j < 8; j++) Vs[((sf8[cc] + j) << 6) | svcol[cc]] = vreg[cc][j];
      }
      __syncthreads();  // next tile staged
    }
  }

  // ---- epilogue: normalize and write [B*S, H*64] bf16 ----
  const int qrow0 = (qt << 6) + (w << 4) + (g4 << 2);
#pragma unroll
  for (int r = 0; r < 4; r++) {
    const float inv = 1.f / lreg[r];
#pragma unroll
    for (int f = 0; f < 4; f++) {
      float v = acc_o[f][r] * inv;
      ao[(size_t)((b << 11) + qrow0 + r) * 1024 + (h << 6) + f * 16 + r16] = (bf16)v;
    }
  }
}

// -----------------------------------------------------------------------------
extern "C" void kernel_launch(void* const* d_in, const int* in_sizes, int n_in,
                              void* d_out, int out_size, void* d_ws, size_t ws_size,
                              hipStream_t stream) {
  const float* query = (const float*)d_in[0];
  const float* key   = (const float*)d_in[1];
  const float* value = (const float*)d_in[2];
  const int*   mask  = (const int*)d_in[3];
  const float* Wq = (const float*)d_in[4];
  const float* bq = (const float*)d_in[5];
  const float* Wk = (const float*)d_in[6];
  const float* bk = (const float*)d_in[7];
  const float* Wv = (const float*)d_in[8];
  const float* bv = (const float*)d_in[9];
  const float* Wo = (const float*)d_in[10];
  const float* bo = (const float*)d_in[11];
  const float* rel = (const float*)d_in[12];

  char* ws = (char*)d_ws;
  bf16* Qb = (bf16*)ws;                                  // 8.4 MB [B*H,S,64]
  bf16* Kb = (bf16*)(ws + 8388608);                      // 8.4 MB
  bf16* Vb = (bf16*)(ws + 16777216);                     // 8.4 MB
  bf16* AO = (bf16*)(ws + 25165824);                     // 8.4 MB [B*S,1024]
  unsigned long long* PM = (unsigned long long*)(ws + 33554432);  // 1 MB
  bf16* qc  = (bf16*)(ws + 34603008);                    // 8.4 MB bf16 query
  bf16* kc  = (bf16*)(ws + 42991616);                    // 8.4 MB bf16 key
  bf16* vc  = (bf16*)(ws + 51380224);                    // 8.4 MB bf16 value
  bf16* wqc = (bf16*)(ws + 59768832);                    // 2 MB
  bf16* wkc = (bf16*)(ws + 61865984);                    // 2 MB
  bf16* wvc = (bf16*)(ws + 63963136);                    // 2 MB
  bf16* woc = (bf16*)(ws + 66060288);                    // 2 MB

  cvt_bf16<<<dim3(256, 7), 256, 0, stream>>>(query, key, value, Wq, Wk, Wv, Wo,
                                             qc, kc, vc, wqc, wkc, wvc, woc);
  pack_mask<<<256, 256, 0, stream>>>(mask, PM, 2 * 2048 * 32);

  dim3 g(32, 16);
  gemm_bt<1><<<g, 256, 0, stream>>>(qc, wqc, bq, Qb);
  gemm_bt<1><<<g, 256, 0, stream>>>(kc, wkc, bk, Kb);
  gemm_bt<1><<<g, 256, 0, stream>>>(vc, wvc, bv, Vb);

  attn_fwd<<<dim3(32, 32), 256, 0, stream>>>(Qb, Kb, Vb, PM, rel, AO);

  gemm_bt<0><<<g, 256, 0, stream>>>(AO, woc, bo, (float*)d_out);
}